// Round 11
// baseline (344.915 us; speedup 1.0000x reference)
//
#include <hip/hip_runtime.h>
#include <hip/hip_bf16.h>

#define NODES 100000
#define EDGES 1600000
#define NBINS ((NODES + 255) >> 8)              // 391 coarse bins, 256 nodes each
#define BINCAP 8192                             // LDS capacity per bin (mean 4092)
#define PB_BLOCKS 128
#define PB_CHUNK ((EDGES + PB_BLOCKS - 1) / PB_BLOCKS)  // 12500 edges per block
#define CAST_BLOCKS 12500                       // 3.2M float4 casts / 256
#define WPREP_BLOCKS 176                        // 45056/256 weight-prep blocks

typedef __bf16 bf16x8 __attribute__((ext_vector_type(8)));
typedef float f32x4 __attribute__((ext_vector_type(4)));

__device__ __forceinline__ unsigned short f2b(float f) {
  __hip_bfloat16 h = __float2bfloat16(f);   // RNE
  return __builtin_bit_cast(unsigned short, h);
}
__device__ __forceinline__ float b_lo(unsigned u) { return __uint_as_float(u << 16); }
__device__ __forceinline__ float b_hi(unsigned u) { return __uint_as_float(u & 0xffff0000u); }

// ---------------------------------------------------------------------------
// prep_count: fused x-cast + weight transpose/cast + per-block bin histogram.
// ---------------------------------------------------------------------------
__global__ __launch_bounds__(256) void prep_count(
    const float4* __restrict__ x4, ushort4* __restrict__ xh4,
    const float* __restrict__ W1, const float* __restrict__ W2,
    const float* __restrict__ W3, const float* __restrict__ W4,
    unsigned short* __restrict__ Wt1, unsigned short* __restrict__ Wt2,
    unsigned short* __restrict__ Wt3, unsigned short* __restrict__ Wt4,
    const int* __restrict__ dst, int* __restrict__ partialT) {
  __shared__ int h[NBINS];
  const int b = blockIdx.x;
  if (b < CAST_BLOCKS) {
    int i = b * 256 + threadIdx.x;
    float4 v = x4[i];
    ushort4 o;
    o.x = f2b(v.x); o.y = f2b(v.y); o.z = f2b(v.z); o.w = f2b(v.w);
    xh4[i] = o;
    return;
  }
  if (b < CAST_BLOCKS + WPREP_BLOCKS) {
    int i = (b - CAST_BLOCKS) * 256 + threadIdx.x;
    if (i < 16384) {                       // Wt1 [128][128]
      int n = i >> 7, k = i & 127;
      Wt1[i] = f2b(W1[k * 128 + n]);
    } else if (i < 32768) {                // Wt2 [128][128]
      int j = i - 16384; int n = j >> 7, k = j & 127;
      Wt2[j] = f2b(W2[k * 128 + n]);
    } else if (i < 40960) {                // Wt3 [64][128]  (K=128,N=64)
      int j = i - 32768; int n = j >> 7, k = j & 127;
      Wt3[j] = f2b(W3[k * 64 + n]);
    } else if (i < 45056) {                // Wt4 [64][64]
      int j = i - 40960; int n = j >> 6, k = j & 63;
      Wt4[j] = f2b(W4[k * 64 + n]);
    }
    return;
  }
  // ---- histogram section ----
  const int cb = b - CAST_BLOCKS - WPREP_BLOCKS;
  for (int i = threadIdx.x; i < NBINS; i += 256) h[i] = 0;
  __syncthreads();
  const int beg = cb * PB_CHUNK;
  const int end = min(beg + PB_CHUNK, EDGES);
  for (int e = beg + threadIdx.x; e < end; e += 256)
    atomicAdd(&h[dst[e] >> 8], 1);
  __syncthreads();
  for (int i = threadIdx.x; i < NBINS; i += 256)
    partialT[i * PB_BLOCKS + cb] = h[i];
}

// ---------------------------------------------------------------------------
// scan_blockoff: one block per bin; scan across 128 producer blocks.
// ---------------------------------------------------------------------------
__global__ __launch_bounds__(128) void scan_blockoff(const int* __restrict__ partialT,
                                                     int* __restrict__ blockoffT,
                                                     int* __restrict__ binTotal) {
  __shared__ int s[128];
  const int bin = blockIdx.x;
  const int t = threadIdx.x;
  int v = partialT[bin * PB_BLOCKS + t];
  s[t] = v;
  __syncthreads();
  for (int off = 1; off < 128; off <<= 1) {
    int u = (t >= off) ? s[t - off] : 0;
    __syncthreads();
    s[t] += u;
    __syncthreads();
  }
  blockoffT[bin * PB_BLOCKS + t] = s[t] - v;  // exclusive within bin
  if (t == 127) binTotal[bin] = s[127];
}

// ---------------------------------------------------------------------------
// scan_totals (1 block): scan 391 bin totals -> binStart
// ---------------------------------------------------------------------------
__global__ __launch_bounds__(512) void scan_totals(const int* __restrict__ binTotal,
                                                   int* __restrict__ binStart,
                                                   int* __restrict__ rowstart) {
  __shared__ int s[512];
  const int t = threadIdx.x;
  int v = (t < NBINS) ? binTotal[t] : 0;
  s[t] = v;
  __syncthreads();
  for (int off = 1; off < 512; off <<= 1) {
    int u = (t >= off) ? s[t - off] : 0;
    __syncthreads();
    s[t] += u;
    __syncthreads();
  }
  if (t < NBINS) binStart[t] = s[t] - v;
  if (t == 0) {
    binStart[NBINS] = EDGES;
    rowstart[NODES] = EDGES;
  }
}

// ---------------------------------------------------------------------------
// CSR pass B: scatter edges into coarse bins (no global atomics)
// ---------------------------------------------------------------------------
__global__ __launch_bounds__(256) void bin_scatter(const int* __restrict__ src,
                                                   const int* __restrict__ dst,
                                                   const int* __restrict__ binStart,
                                                   const int* __restrict__ blockoffT,
                                                   unsigned* __restrict__ coarse) {
  __shared__ int base[NBINS];
  __shared__ int h[NBINS];
  const int beg = blockIdx.x * PB_CHUNK;
  const int end = min(beg + PB_CHUNK, EDGES);
  for (int i = threadIdx.x; i < NBINS; i += 256) {
    base[i] = binStart[i] + blockoffT[i * PB_BLOCKS + blockIdx.x];
    h[i] = 0;
  }
  __syncthreads();
  for (int e = beg + threadIdx.x; e < end; e += 256) {
    int d = dst[e];
    int b = d >> 8;
    int pos = base[b] + atomicAdd(&h[b], 1);
    coarse[pos] = (unsigned)src[e] | ((unsigned)(d & 255) << 17);
  }
}

// ---------------------------------------------------------------------------
// CSR pass C: one block per bin, LDS counting sort -> rowstart + bucket
// ---------------------------------------------------------------------------
__global__ __launch_bounds__(256) void bin_fine(const unsigned* __restrict__ coarse,
                                                const int* __restrict__ binStart,
                                                int* __restrict__ rowstart,
                                                int* __restrict__ bucket) {
  __shared__ unsigned ent[BINCAP];
  __shared__ unsigned obuf[BINCAP];
  __shared__ int deg[256];
  __shared__ int pre[256];
  const int b = blockIdx.x;
  const int t = threadIdx.x;
  const int s0 = binStart[b];
  const int nE = binStart[b + 1] - s0;
  const int binBase = b << 8;

  deg[t] = 0;
  __syncthreads();
  for (int i = t; i < nE; i += 256) {
    unsigned e = coarse[s0 + i];
    ent[i] = e;
    atomicAdd(&deg[e >> 17], 1);
  }
  __syncthreads();
  int v = deg[t];
  pre[t] = v;
  __syncthreads();
  for (int off = 1; off < 256; off <<= 1) {
    int u = (t >= off) ? pre[t - off] : 0;
    __syncthreads();
    pre[t] += u;
    __syncthreads();
  }
  int ex = pre[t] - v;
  if (binBase + t < NODES) rowstart[binBase + t] = s0 + ex;
  deg[t] = ex;  // reuse as cursor
  __syncthreads();
  for (int i = t; i < nE; i += 256) {
    unsigned e = ent[i];
    int pos = atomicAdd(&deg[e >> 17], 1);
    obuf[pos] = e & 0x1FFFFu;
  }
  __syncthreads();
  for (int i = t; i < nE; i += 256) bucket[s0 + i] = (int)obuf[i];
}

// ---------------------------------------------------------------------------
// bf16 gather aggregation, one node per wave, 16 edges per iteration
// (4 independent x-row loads in flight per lane). Unchanged from R10.
// ---------------------------------------------------------------------------
__global__ __launch_bounds__(256) void gather_sum_bf16(
    const uint4* __restrict__ xq, const int* __restrict__ rowstart,
    const int* __restrict__ bucket, uint4* __restrict__ outq) {
  const int n = blockIdx.x * 4 + (threadIdx.x >> 6);
  if (n >= NODES) return;
  const int lane = threadIdx.x & 63;
  const int g = lane >> 4;
  const int fl = lane & 15;

  float a[8] = {0.f, 0.f, 0.f, 0.f, 0.f, 0.f, 0.f, 0.f};
  if (g == 0) {  // self row counted once
    uint4 v = xq[(size_t)n * 16 + fl];
    a[0] = b_lo(v.x); a[1] = b_hi(v.x);
    a[2] = b_lo(v.y); a[3] = b_hi(v.y);
    a[4] = b_lo(v.z); a[5] = b_hi(v.z);
    a[6] = b_lo(v.w); a[7] = b_hi(v.w);
  }

  const int beg = rowstart[n];
  const int end = rowstart[n + 1];
  for (int j = beg; j < end; j += 16) {
    int e0 = j + g, e1 = j + 4 + g, e2 = j + 8 + g, e3 = j + 12 + g;
    int i0 = (e0 < end) ? e0 : (end - 1);
    int i1 = (e1 < end) ? e1 : (end - 1);
    int i2 = (e2 < end) ? e2 : (end - 1);
    int i3 = (e3 < end) ? e3 : (end - 1);
    int s0 = bucket[i0], s1 = bucket[i1], s2 = bucket[i2], s3 = bucket[i3];
    uint4 v0 = xq[(size_t)s0 * 16 + fl];
    uint4 v1 = xq[(size_t)s1 * 16 + fl];
    uint4 v2 = xq[(size_t)s2 * 16 + fl];
    uint4 v3 = xq[(size_t)s3 * 16 + fl];
    float m0 = (e0 < end) ? 1.f : 0.f;
    float m1 = (e1 < end) ? 1.f : 0.f;
    float m2 = (e2 < end) ? 1.f : 0.f;
    float m3 = (e3 < end) ? 1.f : 0.f;
    a[0] = fmaf(b_lo(v0.x), m0, a[0]); a[1] = fmaf(b_hi(v0.x), m0, a[1]);
    a[2] = fmaf(b_lo(v0.y), m0, a[2]); a[3] = fmaf(b_hi(v0.y), m0, a[3]);
    a[4] = fmaf(b_lo(v0.z), m0, a[4]); a[5] = fmaf(b_hi(v0.z), m0, a[5]);
    a[6] = fmaf(b_lo(v0.w), m0, a[6]); a[7] = fmaf(b_hi(v0.w), m0, a[7]);
    a[0] = fmaf(b_lo(v1.x), m1, a[0]); a[1] = fmaf(b_hi(v1.x), m1, a[1]);
    a[2] = fmaf(b_lo(v1.y), m1, a[2]); a[3] = fmaf(b_hi(v1.y), m1, a[3]);
    a[4] = fmaf(b_lo(v1.z), m1, a[4]); a[5] = fmaf(b_hi(v1.z), m1, a[5]);
    a[6] = fmaf(b_lo(v1.w), m1, a[6]); a[7] = fmaf(b_hi(v1.w), m1, a[7]);
    a[0] = fmaf(b_lo(v2.x), m2, a[0]); a[1] = fmaf(b_hi(v2.x), m2, a[1]);
    a[2] = fmaf(b_lo(v2.y), m2, a[2]); a[3] = fmaf(b_hi(v2.y), m2, a[3]);
    a[4] = fmaf(b_lo(v2.z), m2, a[4]); a[5] = fmaf(b_hi(v2.z), m2, a[5]);
    a[6] = fmaf(b_lo(v2.w), m2, a[6]); a[7] = fmaf(b_hi(v2.w), m2, a[7]);
    a[0] = fmaf(b_lo(v3.x), m3, a[0]); a[1] = fmaf(b_hi(v3.x), m3, a[1]);
    a[2] = fmaf(b_lo(v3.y), m3, a[2]); a[3] = fmaf(b_hi(v3.y), m3, a[3]);
    a[4] = fmaf(b_lo(v3.z), m3, a[4]); a[5] = fmaf(b_hi(v3.z), m3, a[5]);
    a[6] = fmaf(b_lo(v3.w), m3, a[6]); a[7] = fmaf(b_hi(v3.w), m3, a[7]);
  }

#pragma unroll
  for (int k = 0; k < 8; k++) {
    a[k] += __shfl_xor(a[k], 16, 64);
    a[k] += __shfl_xor(a[k], 32, 64);
  }

  if (lane < 16) {
    uint4 o;
    o.x = ((unsigned)f2b(a[1]) << 16) | f2b(a[0]);
    o.y = ((unsigned)f2b(a[3]) << 16) | f2b(a[2]);
    o.z = ((unsigned)f2b(a[5]) << 16) | f2b(a[4]);
    o.w = ((unsigned)f2b(a[7]) << 16) | f2b(a[6]);
    outq[(size_t)n * 16 + fl] = o;
  }
}

// ---------------------------------------------------------------------------
// Fused 2-layer MLP v3: out = relu( relu(A @ Wa^T + ba) @ Wb^T + bb )
// Whole weight matrix staged in LDS once per GEMM (padded rows: 2-way bank
// access = free). NO per-K-slice barriers: 3 barriers total vs 14 in v2,
// and each weight stage is one fully-overlapped load burst.
// LDS: layer1 = 17.4 + 34.8 KB -> 3 blocks/CU; layer2 = 17.4+17.4 -> 4.
// ---------------------------------------------------------------------------
template <int K, int N1, int N2, bool OUT_F32>
__global__ __launch_bounds__(256, 3) void mlp_fused(
    const unsigned short* __restrict__ A,
    const unsigned short* __restrict__ Wa, const float* __restrict__ ba,
    const unsigned short* __restrict__ Wb, const float* __restrict__ bb,
    void* __restrict__ Cout, int M) {
  constexpr int LDA = K + 8;           // S row stride (shorts)
  constexpr int LWA = K + 8;           // Wa row stride
  constexpr int LWB = N1 + 8;          // Wb row stride
  constexpr int NT1 = N1 / 16, KB1 = K / 32;
  constexpr int NT2 = N2 / 16, KB2 = N1 / 32;
  constexpr int WSH = (N1 * LWA > N2 * LWB) ? N1 * LWA : N2 * LWB;
  __shared__ unsigned short S[64 * LDA];
  __shared__ unsigned short Wl[WSH];

  const int tid = threadIdx.x;
  const int wave = tid >> 6;
  const int lane = tid & 63;
  const int g = lane >> 4;
  const int fl = lane & 15;
  const int rowBase = blockIdx.x * 64;

  // stage A tile + full Wa in one burst (one barrier)
  for (int i = tid; i < 64 * (K / 8); i += 256) {
    int r = i / (K / 8), c = i % (K / 8);
    uint4 v = make_uint4(0, 0, 0, 0);
    if (rowBase + r < M)
      v = ((const uint4*)A)[(size_t)(rowBase + r) * (K / 8) + c];
    *(uint4*)&S[r * LDA + c * 8] = v;
  }
  for (int i = tid; i < N1 * (K / 8); i += 256) {
    int n = i / (K / 8), c = i % (K / 8);
    *(uint4*)&Wl[n * LWA + c * 8] = *(const uint4*)&Wa[(size_t)n * K + c * 8];
  }
  __syncthreads();

  const int arow = wave * 16 + fl;

  // ---- GEMM1: t1 = relu(A @ Wa^T + ba)  (no mid-loop barriers) ----
  f32x4 acc[NT1];
#pragma unroll
  for (int c = 0; c < NT1; c++) acc[c] = (f32x4){0.f, 0.f, 0.f, 0.f};
#pragma unroll
  for (int kb = 0; kb < KB1; kb++) {
    bf16x8 av = *(const bf16x8*)&S[arow * LDA + kb * 32 + g * 8];
#pragma unroll
    for (int c = 0; c < NT1; c++) {
      bf16x8 bv = *(const bf16x8*)&Wl[(c * 16 + fl) * LWA + kb * 32 + g * 8];
      acc[c] = __builtin_amdgcn_mfma_f32_16x16x32_bf16(av, bv, acc[c], 0, 0, 0);
    }
  }

  // writeback t1 into wave-private rows of S (safe: rows fully consumed)
#pragma unroll
  for (int c = 0; c < NT1; c++) {
    int col = c * 16 + fl;
    float bv = ba[col];
#pragma unroll
    for (int reg = 0; reg < 4; reg++) {
      int rloc = wave * 16 + g * 4 + reg;
      S[rloc * LDA + col] = f2b(fmaxf(acc[c][reg] + bv, 0.f));
    }
  }
  __syncthreads();  // all waves done reading Wa

  // stage full Wb over the Wa region
  for (int i = tid; i < N2 * (N1 / 8); i += 256) {
    int n = i / (N1 / 8), c = i % (N1 / 8);
    *(uint4*)&Wl[n * LWB + c * 8] = *(const uint4*)&Wb[(size_t)n * N1 + c * 8];
  }
  __syncthreads();

  // ---- GEMM2: out = relu(t1 @ Wb^T + bb)  (no mid-loop barriers) ----
  f32x4 acc2[NT2];
#pragma unroll
  for (int c = 0; c < NT2; c++) acc2[c] = (f32x4){0.f, 0.f, 0.f, 0.f};
#pragma unroll
  for (int kb = 0; kb < KB2; kb++) {
    bf16x8 av = *(const bf16x8*)&S[arow * LDA + kb * 32 + g * 8];
#pragma unroll
    for (int c = 0; c < NT2; c++) {
      bf16x8 bv = *(const bf16x8*)&Wl[(c * 16 + fl) * LWB + kb * 32 + g * 8];
      acc2[c] = __builtin_amdgcn_mfma_f32_16x16x32_bf16(av, bv, acc2[c], 0, 0, 0);
    }
  }

#pragma unroll
  for (int c = 0; c < NT2; c++) {
    int col = c * 16 + fl;
    float bv = bb[col];
#pragma unroll
    for (int reg = 0; reg < 4; reg++) {
      int row = rowBase + wave * 16 + g * 4 + reg;
      if (row < M) {
        float v = fmaxf(acc2[c][reg] + bv, 0.f);
        if (OUT_F32)
          ((float*)Cout)[(size_t)row * N2 + col] = v;
        else
          ((unsigned short*)Cout)[(size_t)row * N2 + col] = f2b(v);
      }
    }
  }
}

// ---------------------------------------------------------------------------
// launch
// ---------------------------------------------------------------------------
extern "C" void kernel_launch(void* const* d_in, const int* in_sizes, int n_in,
                              void* d_out, int out_size, void* d_ws, size_t ws_size,
                              hipStream_t stream) {
  const float* x = (const float*)d_in[0];
  const int* ei = (const int*)d_in[1];
  const int* src = ei;               // edge_index[0]
  const int* dst = ei + EDGES;       // edge_index[1]
  const float* W1 = (const float*)d_in[2];
  const float* b1 = (const float*)d_in[3];
  const float* W2 = (const float*)d_in[4];
  const float* b2 = (const float*)d_in[5];
  const float* W3 = (const float*)d_in[6];
  const float* b3 = (const float*)d_in[7];
  const float* W4 = (const float*)d_in[8];
  const float* b4 = (const float*)d_in[9];
  float* out = (float*)d_out;

  // ---- workspace layout (16B-aligned blocks) ----
  char* ws = (char*)d_ws;
  unsigned short* xh = (unsigned short*)ws;                       // 100000*128 bf16
  unsigned short* hA = xh + (size_t)NODES * 128;
  unsigned short* hB = hA + (size_t)NODES * 128;
  unsigned short* Wt1 = hB + (size_t)NODES * 128;                 // 128*128
  unsigned short* Wt2 = Wt1 + 128 * 128;                          // 128*128
  unsigned short* Wt3 = Wt2 + 128 * 128;                          // 64*128
  unsigned short* Wt4 = Wt3 + 64 * 128;                           // 64*64
  int* rowstart = (int*)(Wt4 + 64 * 64);                          // NODES+1
  int* binStart = rowstart + NODES + 1;                           // NBINS+1
  int* binTotal = binStart + NBINS + 1;                           // NBINS
  int* partialT = binTotal + NBINS;                               // NBINS*PB_BLOCKS
  int* blockoffT = partialT + NBINS * PB_BLOCKS;                  // NBINS*PB_BLOCKS
  unsigned* coarse = (unsigned*)(blockoffT + NBINS * PB_BLOCKS);  // EDGES
  int* bucket = (int*)(coarse + EDGES);                           // EDGES

  const int nblocks4 = (NODES + 3) / 4;
  const int gblocks = (NODES + 63) / 64;

  // ---- prep + CSR build ----
  prep_count<<<CAST_BLOCKS + WPREP_BLOCKS + PB_BLOCKS, 256, 0, stream>>>(
      (const float4*)x, (ushort4*)xh, W1, W2, W3, W4, Wt1, Wt2, Wt3, Wt4,
      dst, partialT);
  scan_blockoff<<<NBINS, 128, 0, stream>>>(partialT, blockoffT, binTotal);
  scan_totals<<<1, 512, 0, stream>>>(binTotal, binStart, rowstart);
  bin_scatter<<<PB_BLOCKS, 256, 0, stream>>>(src, dst, binStart, blockoffT, coarse);
  bin_fine<<<NBINS, 256, 0, stream>>>(coarse, binStart, rowstart, bucket);

  // ---- layer 1 ----
  gather_sum_bf16<<<nblocks4, 256, 0, stream>>>((const uint4*)xh, rowstart, bucket,
                                                (uint4*)hA);                     // h_pre1
  mlp_fused<128, 128, 128, false><<<gblocks, 256, 0, stream>>>(
      hA, Wt1, b1, Wt2, b2, hB, NODES);                                          // h1

  // ---- layer 2 ----
  gather_sum_bf16<<<nblocks4, 256, 0, stream>>>((const uint4*)hB, rowstart, bucket,
                                                (uint4*)hA);                     // h_pre2
  mlp_fused<128, 64, 64, true><<<gblocks, 256, 0, stream>>>(
      hA, Wt3, b3, Wt4, b4, out, NODES);                                         // out (f32)
}

// Round 12
// 337.746 us; speedup vs baseline: 1.0212x; 1.0212x over previous
//
#include <hip/hip_runtime.h>
#include <hip/hip_bf16.h>

#define NODES 100000
#define EDGES 1600000
#define NBINS ((NODES + 127) >> 7)              // 782 coarse bins, 128 nodes each
#define BINCAP 4096                             // LDS capacity per bin (mean 2046)
#define PB_BLOCKS 256
#define PB_CHUNK ((EDGES + PB_BLOCKS - 1) / PB_BLOCKS)  // 6250 edges per block
#define CAST_BLOCKS 12500                       // 3.2M float4 casts / 256
#define WPREP_BLOCKS 176                        // 45056/256 weight-prep blocks

typedef __bf16 bf16x8 __attribute__((ext_vector_type(8)));
typedef float f32x4 __attribute__((ext_vector_type(4)));

__device__ __forceinline__ unsigned short f2b(float f) {
  __hip_bfloat16 h = __float2bfloat16(f);   // RNE
  return __builtin_bit_cast(unsigned short, h);
}
__device__ __forceinline__ float b_lo(unsigned u) { return __uint_as_float(u << 16); }
__device__ __forceinline__ float b_hi(unsigned u) { return __uint_as_float(u & 0xffff0000u); }

// ---------------------------------------------------------------------------
// prep_count: fused x-cast + weight transpose/cast + per-block bin histogram.
// ---------------------------------------------------------------------------
__global__ __launch_bounds__(256) void prep_count(
    const float4* __restrict__ x4, ushort4* __restrict__ xh4,
    const float* __restrict__ W1, const float* __restrict__ W2,
    const float* __restrict__ W3, const float* __restrict__ W4,
    unsigned short* __restrict__ Wt1, unsigned short* __restrict__ Wt2,
    unsigned short* __restrict__ Wt3, unsigned short* __restrict__ Wt4,
    const int* __restrict__ dst, int* __restrict__ partialT) {
  __shared__ int h[NBINS];
  const int b = blockIdx.x;
  if (b < CAST_BLOCKS) {
    int i = b * 256 + threadIdx.x;
    float4 v = x4[i];
    ushort4 o;
    o.x = f2b(v.x); o.y = f2b(v.y); o.z = f2b(v.z); o.w = f2b(v.w);
    xh4[i] = o;
    return;
  }
  if (b < CAST_BLOCKS + WPREP_BLOCKS) {
    int i = (b - CAST_BLOCKS) * 256 + threadIdx.x;
    if (i < 16384) {                       // Wt1 [128][128]
      int n = i >> 7, k = i & 127;
      Wt1[i] = f2b(W1[k * 128 + n]);
    } else if (i < 32768) {                // Wt2 [128][128]
      int j = i - 16384; int n = j >> 7, k = j & 127;
      Wt2[j] = f2b(W2[k * 128 + n]);
    } else if (i < 40960) {                // Wt3 [64][128]  (K=128,N=64)
      int j = i - 32768; int n = j >> 7, k = j & 127;
      Wt3[j] = f2b(W3[k * 64 + n]);
    } else if (i < 45056) {                // Wt4 [64][64]
      int j = i - 40960; int n = j >> 6, k = j & 63;
      Wt4[j] = f2b(W4[k * 64 + n]);
    }
    return;
  }
  // ---- histogram section ----
  const int cb = b - CAST_BLOCKS - WPREP_BLOCKS;
  for (int i = threadIdx.x; i < NBINS; i += 256) h[i] = 0;
  __syncthreads();
  const int beg = cb * PB_CHUNK;
  const int end = min(beg + PB_CHUNK, EDGES);
  for (int e = beg + threadIdx.x; e < end; e += 256)
    atomicAdd(&h[dst[e] >> 7], 1);
  __syncthreads();
  for (int i = threadIdx.x; i < NBINS; i += 256)
    partialT[i * PB_BLOCKS + cb] = h[i];
}

// ---------------------------------------------------------------------------
// scan_blockoff: one block per bin; scan across 256 producer blocks.
// ---------------------------------------------------------------------------
__global__ __launch_bounds__(256) void scan_blockoff(const int* __restrict__ partialT,
                                                     int* __restrict__ blockoffT,
                                                     int* __restrict__ binTotal) {
  __shared__ int s[256];
  const int bin = blockIdx.x;
  const int t = threadIdx.x;
  int v = partialT[bin * PB_BLOCKS + t];
  s[t] = v;
  __syncthreads();
  for (int off = 1; off < 256; off <<= 1) {
    int u = (t >= off) ? s[t - off] : 0;
    __syncthreads();
    s[t] += u;
    __syncthreads();
  }
  blockoffT[bin * PB_BLOCKS + t] = s[t] - v;  // exclusive within bin
  if (t == 255) binTotal[bin] = s[255];
}

// ---------------------------------------------------------------------------
// scan_totals (1 block, 1024 thr): scan 782 bin totals -> binStart
// ---------------------------------------------------------------------------
__global__ __launch_bounds__(1024) void scan_totals(const int* __restrict__ binTotal,
                                                    int* __restrict__ binStart,
                                                    int* __restrict__ rowstart) {
  __shared__ int s[1024];
  const int t = threadIdx.x;
  int v = (t < NBINS) ? binTotal[t] : 0;
  s[t] = v;
  __syncthreads();
  for (int off = 1; off < 1024; off <<= 1) {
    int u = (t >= off) ? s[t - off] : 0;
    __syncthreads();
    s[t] += u;
    __syncthreads();
  }
  if (t < NBINS) binStart[t] = s[t] - v;
  if (t == 0) {
    binStart[NBINS] = EDGES;
    rowstart[NODES] = EDGES;
  }
}

// ---------------------------------------------------------------------------
// CSR pass B: scatter edges into coarse bins (no global atomics)
// ---------------------------------------------------------------------------
__global__ __launch_bounds__(256) void bin_scatter(const int* __restrict__ src,
                                                   const int* __restrict__ dst,
                                                   const int* __restrict__ binStart,
                                                   const int* __restrict__ blockoffT,
                                                   unsigned* __restrict__ coarse) {
  __shared__ int base[NBINS];
  __shared__ int h[NBINS];
  const int beg = blockIdx.x * PB_CHUNK;
  const int end = min(beg + PB_CHUNK, EDGES);
  for (int i = threadIdx.x; i < NBINS; i += 256) {
    base[i] = binStart[i] + blockoffT[i * PB_BLOCKS + blockIdx.x];
    h[i] = 0;
  }
  __syncthreads();
  for (int e = beg + threadIdx.x; e < end; e += 256) {
    int d = dst[e];
    int b = d >> 7;
    int pos = base[b] + atomicAdd(&h[b], 1);
    coarse[pos] = (unsigned)src[e] | ((unsigned)(d & 127) << 17);
  }
}

// ---------------------------------------------------------------------------
// CSR pass C: one block per bin (128 nodes), LDS counting sort.
// LDS ~34 KB -> 4 blocks/CU (2x R11's occupancy), 782-way parallel.
// ---------------------------------------------------------------------------
__global__ __launch_bounds__(256) void bin_fine(const unsigned* __restrict__ coarse,
                                                const int* __restrict__ binStart,
                                                int* __restrict__ rowstart,
                                                int* __restrict__ bucket) {
  __shared__ unsigned ent[BINCAP];
  __shared__ unsigned obuf[BINCAP];
  __shared__ int deg[128];
  __shared__ int pre[128];
  const int b = blockIdx.x;
  const int t = threadIdx.x;
  const int s0 = binStart[b];
  const int nE = binStart[b + 1] - s0;
  const int binBase = b << 7;

  if (t < 128) deg[t] = 0;
  __syncthreads();
  for (int i = t; i < nE; i += 256) {
    unsigned e = coarse[s0 + i];
    ent[i] = e;
    atomicAdd(&deg[e >> 17], 1);
  }
  __syncthreads();
  int v = 0;
  if (t < 128) {
    v = deg[t];
    pre[t] = v;
  }
  __syncthreads();
  for (int off = 1; off < 128; off <<= 1) {
    int u = (t >= off && t < 128) ? pre[t - off] : 0;
    __syncthreads();
    if (t < 128) pre[t] += u;
    __syncthreads();
  }
  if (t < 128) {
    int ex = pre[t] - v;
    if (binBase + t < NODES) rowstart[binBase + t] = s0 + ex;
    deg[t] = ex;  // reuse as cursor
  }
  __syncthreads();
  for (int i = t; i < nE; i += 256) {
    unsigned e = ent[i];
    int pos = atomicAdd(&deg[e >> 17], 1);
    obuf[pos] = e & 0x1FFFFu;
  }
  __syncthreads();
  for (int i = t; i < nE; i += 256) bucket[s0 + i] = (int)obuf[i];
}

// ---------------------------------------------------------------------------
// bf16 gather aggregation, one node per wave, 16 edges per iteration
// (4 independent x-row loads in flight per lane). Unchanged from R10.
// ---------------------------------------------------------------------------
__global__ __launch_bounds__(256) void gather_sum_bf16(
    const uint4* __restrict__ xq, const int* __restrict__ rowstart,
    const int* __restrict__ bucket, uint4* __restrict__ outq) {
  const int n = blockIdx.x * 4 + (threadIdx.x >> 6);
  if (n >= NODES) return;
  const int lane = threadIdx.x & 63;
  const int g = lane >> 4;
  const int fl = lane & 15;

  float a[8] = {0.f, 0.f, 0.f, 0.f, 0.f, 0.f, 0.f, 0.f};
  if (g == 0) {  // self row counted once
    uint4 v = xq[(size_t)n * 16 + fl];
    a[0] = b_lo(v.x); a[1] = b_hi(v.x);
    a[2] = b_lo(v.y); a[3] = b_hi(v.y);
    a[4] = b_lo(v.z); a[5] = b_hi(v.z);
    a[6] = b_lo(v.w); a[7] = b_hi(v.w);
  }

  const int beg = rowstart[n];
  const int end = rowstart[n + 1];
  for (int j = beg; j < end; j += 16) {
    int e0 = j + g, e1 = j + 4 + g, e2 = j + 8 + g, e3 = j + 12 + g;
    int i0 = (e0 < end) ? e0 : (end - 1);
    int i1 = (e1 < end) ? e1 : (end - 1);
    int i2 = (e2 < end) ? e2 : (end - 1);
    int i3 = (e3 < end) ? e3 : (end - 1);
    int s0 = bucket[i0], s1 = bucket[i1], s2 = bucket[i2], s3 = bucket[i3];
    uint4 v0 = xq[(size_t)s0 * 16 + fl];
    uint4 v1 = xq[(size_t)s1 * 16 + fl];
    uint4 v2 = xq[(size_t)s2 * 16 + fl];
    uint4 v3 = xq[(size_t)s3 * 16 + fl];
    float m0 = (e0 < end) ? 1.f : 0.f;
    float m1 = (e1 < end) ? 1.f : 0.f;
    float m2 = (e2 < end) ? 1.f : 0.f;
    float m3 = (e3 < end) ? 1.f : 0.f;
    a[0] = fmaf(b_lo(v0.x), m0, a[0]); a[1] = fmaf(b_hi(v0.x), m0, a[1]);
    a[2] = fmaf(b_lo(v0.y), m0, a[2]); a[3] = fmaf(b_hi(v0.y), m0, a[3]);
    a[4] = fmaf(b_lo(v0.z), m0, a[4]); a[5] = fmaf(b_hi(v0.z), m0, a[5]);
    a[6] = fmaf(b_lo(v0.w), m0, a[6]); a[7] = fmaf(b_hi(v0.w), m0, a[7]);
    a[0] = fmaf(b_lo(v1.x), m1, a[0]); a[1] = fmaf(b_hi(v1.x), m1, a[1]);
    a[2] = fmaf(b_lo(v1.y), m1, a[2]); a[3] = fmaf(b_hi(v1.y), m1, a[3]);
    a[4] = fmaf(b_lo(v1.z), m1, a[4]); a[5] = fmaf(b_hi(v1.z), m1, a[5]);
    a[6] = fmaf(b_lo(v1.w), m1, a[6]); a[7] = fmaf(b_hi(v1.w), m1, a[7]);
    a[0] = fmaf(b_lo(v2.x), m2, a[0]); a[1] = fmaf(b_hi(v2.x), m2, a[1]);
    a[2] = fmaf(b_lo(v2.y), m2, a[2]); a[3] = fmaf(b_hi(v2.y), m2, a[3]);
    a[4] = fmaf(b_lo(v2.z), m2, a[4]); a[5] = fmaf(b_hi(v2.z), m2, a[5]);
    a[6] = fmaf(b_lo(v2.w), m2, a[6]); a[7] = fmaf(b_hi(v2.w), m2, a[7]);
    a[0] = fmaf(b_lo(v3.x), m3, a[0]); a[1] = fmaf(b_hi(v3.x), m3, a[1]);
    a[2] = fmaf(b_lo(v3.y), m3, a[2]); a[3] = fmaf(b_hi(v3.y), m3, a[3]);
    a[4] = fmaf(b_lo(v3.z), m3, a[4]); a[5] = fmaf(b_hi(v3.z), m3, a[5]);
    a[6] = fmaf(b_lo(v3.w), m3, a[6]); a[7] = fmaf(b_hi(v3.w), m3, a[7]);
  }

#pragma unroll
  for (int k = 0; k < 8; k++) {
    a[k] += __shfl_xor(a[k], 16, 64);
    a[k] += __shfl_xor(a[k], 32, 64);
  }

  if (lane < 16) {
    uint4 o;
    o.x = ((unsigned)f2b(a[1]) << 16) | f2b(a[0]);
    o.y = ((unsigned)f2b(a[3]) << 16) | f2b(a[2]);
    o.z = ((unsigned)f2b(a[5]) << 16) | f2b(a[4]);
    o.w = ((unsigned)f2b(a[7]) << 16) | f2b(a[6]);
    outq[(size_t)n * 16 + fl] = o;
  }
}

// ---------------------------------------------------------------------------
// Fused 2-layer MLP v3: out = relu( relu(A @ Wa^T + ba) @ Wb^T + bb )
// Whole weight matrix staged in LDS once per GEMM; 3 barriers total.
// ---------------------------------------------------------------------------
template <int K, int N1, int N2, bool OUT_F32>
__global__ __launch_bounds__(256, 3) void mlp_fused(
    const unsigned short* __restrict__ A,
    const unsigned short* __restrict__ Wa, const float* __restrict__ ba,
    const unsigned short* __restrict__ Wb, const float* __restrict__ bb,
    void* __restrict__ Cout, int M) {
  constexpr int LDA = K + 8;           // S row stride (shorts)
  constexpr int LWA = K + 8;           // Wa row stride
  constexpr int LWB = N1 + 8;          // Wb row stride
  constexpr int NT1 = N1 / 16, KB1 = K / 32;
  constexpr int NT2 = N2 / 16, KB2 = N1 / 32;
  constexpr int WSH = (N1 * LWA > N2 * LWB) ? N1 * LWA : N2 * LWB;
  __shared__ unsigned short S[64 * LDA];
  __shared__ unsigned short Wl[WSH];

  const int tid = threadIdx.x;
  const int wave = tid >> 6;
  const int lane = tid & 63;
  const int g = lane >> 4;
  const int fl = lane & 15;
  const int rowBase = blockIdx.x * 64;

  // stage A tile + full Wa in one burst (one barrier)
  for (int i = tid; i < 64 * (K / 8); i += 256) {
    int r = i / (K / 8), c = i % (K / 8);
    uint4 v = make_uint4(0, 0, 0, 0);
    if (rowBase + r < M)
      v = ((const uint4*)A)[(size_t)(rowBase + r) * (K / 8) + c];
    *(uint4*)&S[r * LDA + c * 8] = v;
  }
  for (int i = tid; i < N1 * (K / 8); i += 256) {
    int n = i / (K / 8), c = i % (K / 8);
    *(uint4*)&Wl[n * LWA + c * 8] = *(const uint4*)&Wa[(size_t)n * K + c * 8];
  }
  __syncthreads();

  const int arow = wave * 16 + fl;

  // ---- GEMM1: t1 = relu(A @ Wa^T + ba)  (no mid-loop barriers) ----
  f32x4 acc[NT1];
#pragma unroll
  for (int c = 0; c < NT1; c++) acc[c] = (f32x4){0.f, 0.f, 0.f, 0.f};
#pragma unroll
  for (int kb = 0; kb < KB1; kb++) {
    bf16x8 av = *(const bf16x8*)&S[arow * LDA + kb * 32 + g * 8];
#pragma unroll
    for (int c = 0; c < NT1; c++) {
      bf16x8 bv = *(const bf16x8*)&Wl[(c * 16 + fl) * LWA + kb * 32 + g * 8];
      acc[c] = __builtin_amdgcn_mfma_f32_16x16x32_bf16(av, bv, acc[c], 0, 0, 0);
    }
  }

  // writeback t1 into wave-private rows of S (safe: rows fully consumed)
#pragma unroll
  for (int c = 0; c < NT1; c++) {
    int col = c * 16 + fl;
    float bv = ba[col];
#pragma unroll
    for (int reg = 0; reg < 4; reg++) {
      int rloc = wave * 16 + g * 4 + reg;
      S[rloc * LDA + col] = f2b(fmaxf(acc[c][reg] + bv, 0.f));
    }
  }
  __syncthreads();  // all waves done reading Wa

  // stage full Wb over the Wa region
  for (int i = tid; i < N2 * (N1 / 8); i += 256) {
    int n = i / (N1 / 8), c = i % (N1 / 8);
    *(uint4*)&Wl[n * LWB + c * 8] = *(const uint4*)&Wb[(size_t)n * N1 + c * 8];
  }
  __syncthreads();

  // ---- GEMM2: out = relu(t1 @ Wb^T + bb)  (no mid-loop barriers) ----
  f32x4 acc2[NT2];
#pragma unroll
  for (int c = 0; c < NT2; c++) acc2[c] = (f32x4){0.f, 0.f, 0.f, 0.f};
#pragma unroll
  for (int kb = 0; kb < KB2; kb++) {
    bf16x8 av = *(const bf16x8*)&S[arow * LDA + kb * 32 + g * 8];
#pragma unroll
    for (int c = 0; c < NT2; c++) {
      bf16x8 bv = *(const bf16x8*)&Wl[(c * 16 + fl) * LWB + kb * 32 + g * 8];
      acc2[c] = __builtin_amdgcn_mfma_f32_16x16x32_bf16(av, bv, acc2[c], 0, 0, 0);
    }
  }

#pragma unroll
  for (int c = 0; c < NT2; c++) {
    int col = c * 16 + fl;
    float bv = bb[col];
#pragma unroll
    for (int reg = 0; reg < 4; reg++) {
      int row = rowBase + wave * 16 + g * 4 + reg;
      if (row < M) {
        float v = fmaxf(acc2[c][reg] + bv, 0.f);
        if (OUT_F32)
          ((float*)Cout)[(size_t)row * N2 + col] = v;
        else
          ((unsigned short*)Cout)[(size_t)row * N2 + col] = f2b(v);
      }
    }
  }
}

// ---------------------------------------------------------------------------
// launch
// ---------------------------------------------------------------------------
extern "C" void kernel_launch(void* const* d_in, const int* in_sizes, int n_in,
                              void* d_out, int out_size, void* d_ws, size_t ws_size,
                              hipStream_t stream) {
  const float* x = (const float*)d_in[0];
  const int* ei = (const int*)d_in[1];
  const int* src = ei;               // edge_index[0]
  const int* dst = ei + EDGES;       // edge_index[1]
  const float* W1 = (const float*)d_in[2];
  const float* b1 = (const float*)d_in[3];
  const float* W2 = (const float*)d_in[4];
  const float* b2 = (const float*)d_in[5];
  const float* W3 = (const float*)d_in[6];
  const float* b3 = (const float*)d_in[7];
  const float* W4 = (const float*)d_in[8];
  const float* b4 = (const float*)d_in[9];
  float* out = (float*)d_out;

  // ---- workspace layout (16B-aligned blocks) ----
  char* ws = (char*)d_ws;
  unsigned short* xh = (unsigned short*)ws;                       // 100000*128 bf16
  unsigned short* hA = xh + (size_t)NODES * 128;
  unsigned short* hB = hA + (size_t)NODES * 128;
  unsigned short* Wt1 = hB + (size_t)NODES * 128;                 // 128*128
  unsigned short* Wt2 = Wt1 + 128 * 128;                          // 128*128
  unsigned short* Wt3 = Wt2 + 128 * 128;                          // 64*128
  unsigned short* Wt4 = Wt3 + 64 * 128;                           // 64*64
  int* rowstart = (int*)(Wt4 + 64 * 64);                          // NODES+1
  int* binStart = rowstart + NODES + 1;                           // NBINS+1
  int* binTotal = binStart + NBINS + 1;                           // NBINS
  int* partialT = binTotal + NBINS;                               // NBINS*PB_BLOCKS
  int* blockoffT = partialT + NBINS * PB_BLOCKS;                  // NBINS*PB_BLOCKS
  unsigned* coarse = (unsigned*)(blockoffT + NBINS * PB_BLOCKS);  // EDGES
  int* bucket = (int*)(coarse + EDGES);                           // EDGES

  const int nblocks4 = (NODES + 3) / 4;
  const int gblocks = (NODES + 63) / 64;

  // ---- prep + CSR build ----
  prep_count<<<CAST_BLOCKS + WPREP_BLOCKS + PB_BLOCKS, 256, 0, stream>>>(
      (const float4*)x, (ushort4*)xh, W1, W2, W3, W4, Wt1, Wt2, Wt3, Wt4,
      dst, partialT);
  scan_blockoff<<<NBINS, 256, 0, stream>>>(partialT, blockoffT, binTotal);
  scan_totals<<<1, 1024, 0, stream>>>(binTotal, binStart, rowstart);
  bin_scatter<<<PB_BLOCKS, 256, 0, stream>>>(src, dst, binStart, blockoffT, coarse);
  bin_fine<<<NBINS, 256, 0, stream>>>(coarse, binStart, rowstart, bucket);

  // ---- layer 1 ----
  gather_sum_bf16<<<nblocks4, 256, 0, stream>>>((const uint4*)xh, rowstart, bucket,
                                                (uint4*)hA);                     // h_pre1
  mlp_fused<128, 128, 128, false><<<gblocks, 256, 0, stream>>>(
      hA, Wt1, b1, Wt2, b2, hB, NODES);                                          // h1

  // ---- layer 2 ----
  gather_sum_bf16<<<nblocks4, 256, 0, stream>>>((const uint4*)hB, rowstart, bucket,
                                                (uint4*)hA);                     // h_pre2
  mlp_fused<128, 64, 64, true><<<gblocks, 256, 0, stream>>>(
      hA, Wt3, b3, Wt4, b4, out, NODES);                                         // out (f32)
}